// Round 6
// baseline (846.700 us; speedup 1.0000x reference)
//
#include <hip/hip_runtime.h>
#include <hip/hip_bf16.h>
#include <math.h>

#define NN 50000     // nodes
#define NE 400000    // edges
#define HH 4         // heads
#define CC 64        // per-head dim
#define HC 256       // H*C
#define GG 64        // graphs

// ---------------- encoder: h0 = relu(x @ enc_w + enc_b), [N,8]x[8,64] ----------------
__global__ __launch_bounds__(256) void encoder_kernel(
    const float* __restrict__ x, const float* __restrict__ w,
    const float* __restrict__ b, float* __restrict__ h0) {
  int idx = blockIdx.x * 256 + threadIdx.x;   // N*64 threads
  int node = idx >> 6, col = idx & 63;
  const float* xr = x + node * 8;
  float acc = b[col];
#pragma unroll
  for (int k = 0; k < 8; ++k) acc += xr[k] * w[k * 64 + col];
  h0[idx] = fmaxf(acc, 0.f);
}

// ---- fused dual matmul: outL = A@WL + bL, outR = A@WR.  A[M,K], W[K,256] ----
// Block: 16 rows x 256 cols (LDS 16*(K+4)*4 B -> high occupancy; grid 3125).
// Thread: 4 rows x 4 cols x 2 matrices = 32 accumulators. Rows rg+4*i
// (rg = tid&3): KP%32==4 keeps the 4 rg-addresses of each ds_read_b128 on
// disjoint banks. A tile staged ONCE, used for both weight matrices (2x
// arithmetic intensity per LDS byte vs separate kernels).
template <int K>
__global__ __launch_bounds__(256) void matmul2_rb_kernel(
    const float* __restrict__ A,
    const float* __restrict__ WL, const float* __restrict__ biasL,
    const float* __restrict__ WR,
    float* __restrict__ outL, float* __restrict__ outR) {
  constexpr int KP = K + 4;                 // padded row stride; KP%32==4
  __shared__ float a_tile[16 * KP];
  const int tid = threadIdx.x;
  const int rg = tid & 3;
  const int cg = tid >> 2;
  const int r0 = blockIdx.x * 16;

  constexpr int NV = 16 * (K / 4);
  const float4* A4 = (const float4*)A;
  for (int i = tid; i < NV; i += 256) {
    int r = i / (K / 4);
    int kb = i - r * (K / 4);
    float4 v = A4[(size_t)(r0 + r) * (K / 4) + kb];
    *(float4*)&a_tile[r * KP + 4 * kb] = v;
  }
  __syncthreads();

  float accL[4][4], accR[4][4];
#pragma unroll
  for (int i = 0; i < 4; ++i) {
    accL[i][0] = biasL[cg * 4 + 0];
    accL[i][1] = biasL[cg * 4 + 1];
    accL[i][2] = biasL[cg * 4 + 2];
    accL[i][3] = biasL[cg * 4 + 3];
    accR[i][0] = 0.f; accR[i][1] = 0.f; accR[i][2] = 0.f; accR[i][3] = 0.f;
  }

  const float* Arow = &a_tile[rg * KP];     // thread's row i lives at rg + 4*i
  const float* WLp = WL + cg * 4;
  const float* WRp = WR + cg * 4;
  for (int k0 = 0; k0 < K; k0 += 4) {
    float4 a0 = *(const float4*)&Arow[0 * 4 * KP + k0];
    float4 a1 = *(const float4*)&Arow[1 * 4 * KP + k0];
    float4 a2 = *(const float4*)&Arow[2 * 4 * KP + k0];
    float4 a3 = *(const float4*)&Arow[3 * 4 * KP + k0];
    float4 av[4] = {a0, a1, a2, a3};

    float4 w0 = *(const float4*)&WLp[(k0 + 0) * 256];
    float4 w1 = *(const float4*)&WLp[(k0 + 1) * 256];
    float4 w2 = *(const float4*)&WLp[(k0 + 2) * 256];
    float4 w3 = *(const float4*)&WLp[(k0 + 3) * 256];
#pragma unroll
    for (int i = 0; i < 4; ++i) {
      float4 a = av[i];
      accL[i][0] += a.x * w0.x; accL[i][0] += a.y * w1.x;
      accL[i][0] += a.z * w2.x; accL[i][0] += a.w * w3.x;
      accL[i][1] += a.x * w0.y; accL[i][1] += a.y * w1.y;
      accL[i][1] += a.z * w2.y; accL[i][1] += a.w * w3.y;
      accL[i][2] += a.x * w0.z; accL[i][2] += a.y * w1.z;
      accL[i][2] += a.z * w2.z; accL[i][2] += a.w * w3.z;
      accL[i][3] += a.x * w0.w; accL[i][3] += a.y * w1.w;
      accL[i][3] += a.z * w2.w; accL[i][3] += a.w * w3.w;
    }

    w0 = *(const float4*)&WRp[(k0 + 0) * 256];
    w1 = *(const float4*)&WRp[(k0 + 1) * 256];
    w2 = *(const float4*)&WRp[(k0 + 2) * 256];
    w3 = *(const float4*)&WRp[(k0 + 3) * 256];
#pragma unroll
    for (int i = 0; i < 4; ++i) {
      float4 a = av[i];
      accR[i][0] += a.x * w0.x; accR[i][0] += a.y * w1.x;
      accR[i][0] += a.z * w2.x; accR[i][0] += a.w * w3.x;
      accR[i][1] += a.x * w0.y; accR[i][1] += a.y * w1.y;
      accR[i][1] += a.z * w2.y; accR[i][1] += a.w * w3.y;
      accR[i][2] += a.x * w0.z; accR[i][2] += a.y * w1.z;
      accR[i][2] += a.z * w2.z; accR[i][2] += a.w * w3.z;
      accR[i][3] += a.x * w0.w; accR[i][3] += a.y * w1.w;
      accR[i][3] += a.z * w2.w; accR[i][3] += a.w * w3.w;
    }
  }

#pragma unroll
  for (int i = 0; i < 4; ++i) {
    int row = r0 + rg + 4 * i;
    *(float4*)&outL[(size_t)row * 256 + cg * 4] =
        make_float4(accL[i][0], accL[i][1], accL[i][2], accL[i][3]);
    *(float4*)&outR[(size_t)row * 256 + cg * 4] =
        make_float4(accR[i][0], accR[i][1], accR[i][2], accR[i][3]);
  }
}

// ---------------- CSR build ----------------
__global__ void degree_kernel(const int* __restrict__ ei, int* __restrict__ deg) {
  int e = blockIdx.x * 256 + threadIdx.x;
  if (e < NE) atomicAdd(&deg[ei[NE + e]], 1);
}

__global__ __launch_bounds__(1024) void scan_kernel(
    const int* __restrict__ deg, int* __restrict__ rowstart) {
  __shared__ int buf0[1024];
  __shared__ int buf1[1024];
  int tid = threadIdx.x;
  const int per = (NN + 1023) / 1024;  // 49
  int s = tid * per, e = s + per; if (e > NN) e = NN; if (s > NN) s = NN;
  int sum = 0;
  for (int i = s; i < e; ++i) sum += deg[i];
  buf0[tid] = sum;
  __syncthreads();
  int* in = buf0; int* outb = buf1;
  for (int off = 1; off < 1024; off <<= 1) {
    int v = in[tid];
    if (tid >= off) v += in[tid - off];
    outb[tid] = v;
    __syncthreads();
    int* t = in; in = outb; outb = t;
  }
  int excl = in[tid] - sum;
  int run = excl;
  for (int i = s; i < e; ++i) { rowstart[i] = run; run += deg[i]; }
  if (tid == 1023) rowstart[NN] = in[1023];
}

__global__ void cursor_copy_kernel(const int* __restrict__ rowstart, int* __restrict__ cursor) {
  int i = blockIdx.x * 256 + threadIdx.x;
  if (i < NN) cursor[i] = rowstart[i];
}

// CSR fill: also materialize src and edge_attr in CSR order.
__global__ void fill_kernel(const int* __restrict__ ei, const float* __restrict__ ea,
                            int* __restrict__ cursor,
                            int* __restrict__ src_sorted, float* __restrict__ ea_sorted) {
  int e = blockIdx.x * 256 + threadIdx.x;
  if (e < NE) {
    int d = ei[NE + e];
    int pos = atomicAdd(&cursor[d], 1);
    src_sorted[pos] = ei[e];
    ea_sorted[pos] = ea[e];
  }
}

// ---------------- fused GATv2 edge phase: wave per dst node ----------------
__global__ __launch_bounds__(256) void gat_fused_kernel(
    const int* __restrict__ rowstart, const int* __restrict__ src_sorted,
    const float* __restrict__ ea_sorted,
    const float* __restrict__ xl, const float* __restrict__ xr,
    const float* __restrict__ we, const float* __restrict__ att,
    const float* __restrict__ bias, float* __restrict__ out) {
  int node = (blockIdx.x * 256 + threadIdx.x) >> 6;
  int lane = threadIdx.x & 63;
  int r0 = rowstart[node], r1 = rowstart[node + 1];
  const float4* xl4 = (const float4*)xl;
  float4 r = ((const float4*)xr)[node * 64 + lane];
  float4 wv = ((const float4*)we)[lane];
  float4 at = ((const float4*)att)[lane];
  float4 acc = make_float4(0.f, 0.f, 0.f, 0.f);
  float denom = 0.f;

  auto edge_step = [&](float eav, float4 a) {
    float s0 = a.x + r.x + eav * wv.x;
    float s1 = a.y + r.y + eav * wv.y;
    float s2 = a.z + r.z + eav * wv.z;
    float s3 = a.w + r.w + eav * wv.w;
    s0 = s0 > 0.f ? s0 : 0.2f * s0;
    s1 = s1 > 0.f ? s1 : 0.2f * s1;
    s2 = s2 > 0.f ? s2 : 0.2f * s2;
    s3 = s3 > 0.f ? s3 : 0.2f * s3;
    float p = s0 * at.x + s1 * at.y + s2 * at.z + s3 * at.w;
#pragma unroll
    for (int off = 8; off; off >>= 1) p += __shfl_xor(p, off, 16);
    float ex = __expf(p);
    denom += ex;
    acc.x += ex * a.x; acc.y += ex * a.y; acc.z += ex * a.z; acc.w += ex * a.w;
  };

  int i = r0;
  for (; i + 2 <= r1; i += 2) {           // pairwise: 2 gathers in flight
    int s0i = src_sorted[i];
    int s1i = src_sorted[i + 1];
    float e0 = ea_sorted[i];
    float e1 = ea_sorted[i + 1];
    float4 a0 = xl4[(size_t)s0i * 64 + lane];
    float4 a1 = xl4[(size_t)s1i * 64 + lane];
    edge_step(e0, a0);
    edge_step(e1, a1);
  }
  if (i < r1) {
    int s0i = src_sorted[i];
    float e0 = ea_sorted[i];
    float4 a0 = xl4[(size_t)s0i * 64 + lane];
    edge_step(e0, a0);
  }

  float inv = 1.f / (denom + 1e-16f);
  float4 bv = ((const float4*)bias)[lane];
  float4 o;
  o.x = fmaxf(acc.x * inv + bv.x, 0.f);
  o.y = fmaxf(acc.y * inv + bv.y, 0.f);
  o.z = fmaxf(acc.z * inv + bv.z, 0.f);
  o.w = fmaxf(acc.w * inv + bv.w, 0.f);
  ((float4*)out)[(size_t)node * 64 + lane] = o;
}

// ---------------- segment bounds via binary search (batch is sorted) ----------------
__global__ void seg_bounds_kernel(const int* __restrict__ batch, int* __restrict__ bounds) {
  int g = threadIdx.x;                 // 0..GG inclusive
  if (g > GG) return;
  int lo = 0, hi = NN;
  while (lo < hi) {                    // first index with batch[i] >= g
    int mid = (lo + hi) >> 1;
    if (batch[mid] < g) lo = mid + 1; else hi = mid;
  }
  bounds[g] = lo;
}

__global__ __launch_bounds__(256) void pool_kernel(
    const float* __restrict__ h, const int* __restrict__ batch,
    float* __restrict__ pool) {
  int start = blockIdx.x * 256;
  int end = start + 256; if (end > NN) end = NN;
  int tid = threadIdx.x;
  int cur = batch[start];
  float acc = 0.f;
  for (int n = start; n < end; ++n) {
    int b = batch[n];
    if (b != cur) {
      atomicAdd(&pool[cur * 256 + tid], acc);
      acc = 0.f; cur = b;
    }
    acc += h[n * 256 + tid];
  }
  atomicAdd(&pool[cur * 256 + tid], acc);
}

// ---------------- final MLP: one block (128 thr) per graph ----------------
__global__ __launch_bounds__(128) void mlp_kernel(
    const float* __restrict__ pool, const int* __restrict__ bounds,
    const float* __restrict__ p1w, const float* __restrict__ p1b,
    const float* __restrict__ lng, const float* __restrict__ lnb,
    const float* __restrict__ p2w, const float* __restrict__ p2b,
    const float* __restrict__ hw, const float* __restrict__ hb,
    float* __restrict__ out) {
  __shared__ float sg[256];
  __shared__ float red[128];
  __shared__ float sz[128];
  __shared__ float s2[64];
  int b = blockIdx.x, tid = threadIdx.x;
  float cntf = (float)(bounds[b + 1] - bounds[b]);
  float invc = 1.f / fmaxf(cntf, 1.f);
  for (int i = tid; i < 256; i += 128) sg[i] = pool[b * 256 + i] * invc;
  __syncthreads();
  float z = p1b[tid];
  for (int k = 0; k < 256; ++k) z += sg[k] * p1w[k * 128 + tid];
  red[tid] = z; __syncthreads();
  for (int off = 64; off; off >>= 1) { if (tid < off) red[tid] += red[tid + off]; __syncthreads(); }
  float mu = red[0] * (1.f / 128.f);
  __syncthreads();
  float d = z - mu;
  red[tid] = d * d; __syncthreads();
  for (int off = 64; off; off >>= 1) { if (tid < off) red[tid] += red[tid + off]; __syncthreads(); }
  float var = red[0] * (1.f / 128.f);
  float zn = d * rsqrtf(var + 1e-5f) * lng[tid] + lnb[tid];
  sz[tid] = fmaxf(zn, 0.f);
  __syncthreads();
  if (tid < 64) {
    float a = p2b[tid];
    for (int k = 0; k < 128; ++k) a += sz[k] * p2w[k * 64 + tid];
    s2[tid] = fmaxf(a, 0.f);
  }
  __syncthreads();
  if (tid < 64) {
    float p = s2[tid] * hw[tid];
    for (int off = 32; off; off >>= 1) p += __shfl_down(p, off, 64);
    if (tid == 0) out[b] = p + hb[0];
  }
}

extern "C" void kernel_launch(void* const* d_in, const int* in_sizes, int n_in,
                              void* d_out, int out_size, void* d_ws, size_t ws_size,
                              hipStream_t stream) {
  const float* x      = (const float*)d_in[0];
  const int*   ei     = (const int*)d_in[1];
  const float* ea     = (const float*)d_in[2];
  const int*   batch  = (const int*)d_in[3];
  const float* enc_w  = (const float*)d_in[4];
  const float* enc_b  = (const float*)d_in[5];
  const float* g1_wl  = (const float*)d_in[6];
  const float* g1_bl  = (const float*)d_in[7];
  const float* g1_wr  = (const float*)d_in[8];
  const float* g1_we  = (const float*)d_in[9];
  const float* g1_att = (const float*)d_in[10];
  const float* g1_b   = (const float*)d_in[11];
  const float* g2_wl  = (const float*)d_in[12];
  const float* g2_bl  = (const float*)d_in[13];
  const float* g2_wr  = (const float*)d_in[14];
  const float* g2_we  = (const float*)d_in[15];
  const float* g2_att = (const float*)d_in[16];
  const float* g2_b   = (const float*)d_in[17];
  const float* p1_w   = (const float*)d_in[18];
  const float* p1_b   = (const float*)d_in[19];
  const float* ln_g   = (const float*)d_in[20];
  const float* ln_b   = (const float*)d_in[21];
  const float* p2_w   = (const float*)d_in[22];
  const float* p2_b   = (const float*)d_in[23];
  const float* head_w = (const float*)d_in[24];
  const float* head_b = (const float*)d_in[25];
  float* out = (float*)d_out;

  char* ws = (char*)d_ws;
  size_t off = 0;
  auto alloc = [&](size_t bytes) -> void* {
    void* p = ws + off;
    off = (off + bytes + 255) & ~(size_t)255;
    return p;
  };
  float* h0        = (float*)alloc((size_t)NN * 64 * 4);
  float* hbuf      = (float*)alloc((size_t)NN * HC * 4);
  float* xl        = (float*)alloc((size_t)NN * HC * 4);
  float* xr        = (float*)alloc((size_t)NN * HC * 4);
  float* pool      = (float*)alloc((size_t)GG * HC * 4);
  int*   deg       = (int*)alloc((size_t)NN * 4);
  int*   rowstart  = (int*)alloc((size_t)(NN + 1) * 4);
  int*   cursor    = (int*)alloc((size_t)NN * 4);
  int*   src_sorted= (int*)alloc((size_t)NE * 4);
  float* ea_sorted = (float*)alloc((size_t)NE * 4);
  int*   bounds    = (int*)alloc((size_t)(GG + 1) * 4);

  hipMemsetAsync(deg, 0, (size_t)NN * 4, stream);
  hipMemsetAsync(pool, 0, (size_t)GG * HC * 4, stream);

  // encoder
  encoder_kernel<<<NN * 64 / 256, 256, 0, stream>>>(x, enc_w, enc_b, h0);

  // CSR build (shared by both layers)
  degree_kernel<<<(NE + 255) / 256, 256, 0, stream>>>(ei, deg);
  scan_kernel<<<1, 1024, 0, stream>>>(deg, rowstart);
  cursor_copy_kernel<<<(NN + 255) / 256, 256, 0, stream>>>(rowstart, cursor);
  fill_kernel<<<(NE + 255) / 256, 256, 0, stream>>>(ei, ea, cursor, src_sorted, ea_sorted);

  // graph segment bounds (batch is sorted)
  seg_bounds_kernel<<<1, GG + 1, 0, stream>>>(batch, bounds);

  const int MMB = NN / 16;  // 3125 blocks, exact

  // ---- GAT layer 1 (K=64): xl = h0@wl + bl, xr = h0@wr (one fused pass) ----
  matmul2_rb_kernel<64><<<MMB, 256, 0, stream>>>(h0, g1_wl, g1_bl, g1_wr, xl, xr);
  gat_fused_kernel<<<NN / 4, 256, 0, stream>>>(rowstart, src_sorted, ea_sorted,
                                               xl, xr, g1_we, g1_att, g1_b, hbuf);

  // ---- GAT layer 2 (K=256) ----
  matmul2_rb_kernel<256><<<MMB, 256, 0, stream>>>(hbuf, g2_wl, g2_bl, g2_wr, xl, xr);
  gat_fused_kernel<<<NN / 4, 256, 0, stream>>>(rowstart, src_sorted, ea_sorted,
                                               xl, xr, g2_we, g2_att, g2_b, hbuf);

  // ---- pooling + MLP head ----
  pool_kernel<<<(NN + 255) / 256, 256, 0, stream>>>(hbuf, batch, pool);
  mlp_kernel<<<GG, 128, 0, stream>>>(pool, bounds, p1_w, p1_b, ln_g, ln_b,
                                     p2_w, p2_b, head_w, head_b, out);
}

// Round 7
// 706.652 us; speedup vs baseline: 1.1982x; 1.1982x over previous
//
#include <hip/hip_runtime.h>
#include <hip/hip_bf16.h>
#include <math.h>

#define NN 50000     // nodes
#define NE 400000    // edges
#define HH 4         // heads
#define CC 64        // per-head dim
#define HC 256       // H*C
#define GG 64        // graphs

// ---------------- encoder: h0 = relu(x @ enc_w + enc_b), [N,8]x[8,64] ----------------
__global__ __launch_bounds__(256) void encoder_kernel(
    const float* __restrict__ x, const float* __restrict__ w,
    const float* __restrict__ b, float* __restrict__ h0) {
  int idx = blockIdx.x * 256 + threadIdx.x;   // N*64 threads
  int node = idx >> 6, col = idx & 63;
  const float* xr = x + node * 8;
  float acc = b[col];
#pragma unroll
  for (int k = 0; k < 8; ++k) acc += xr[k] * w[k * 64 + col];
  h0[idx] = fmaxf(acc, 0.f);
}

// ---------------- register-blocked matmul: out[M,256] = A[M,K] @ W[K,256] (+bias) ----
// Block: 32 rows x 256 cols. Thread: 8 rows x 4 cols, rows rg+4*i (conflict-free
// LDS reads: KP%32==4). W loads software-pipelined one 4-k chunk ahead (~256 cyc
// of FMA issue covers ~200 cyc L2 latency). 52->~85 VGPR: still >=4 blocks/CU.
template <int K>
__global__ __launch_bounds__(256) void matmul_rb_kernel(
    const float* __restrict__ A, const float* __restrict__ W,
    const float* __restrict__ bias, float* __restrict__ out, int M) {
  constexpr int KP = K + 4;                 // padded row stride; KP%32==4, 16B-aligned
  __shared__ float a_tile[32 * KP];
  const int tid = threadIdx.x;
  const int rg = tid & 3;
  const int cg = tid >> 2;
  const int r0 = blockIdx.x * 32;

  constexpr int NV = 32 * (K / 4);
  const float4* A4 = (const float4*)A;
  for (int i = tid; i < NV; i += 256) {
    int r = i / (K / 4);
    int kb = i - r * (K / 4);
    int row = r0 + r;
    if (row >= M) row = M - 1;              // clamp: value unused on store
    float4 v = A4[(size_t)row * (K / 4) + kb];
    *(float4*)&a_tile[r * KP + 4 * kb] = v;
  }
  __syncthreads();

  float bv0 = bias ? bias[cg * 4 + 0] : 0.f;
  float bv1 = bias ? bias[cg * 4 + 1] : 0.f;
  float bv2 = bias ? bias[cg * 4 + 2] : 0.f;
  float bv3 = bias ? bias[cg * 4 + 3] : 0.f;
  float acc[8][4];
#pragma unroll
  for (int i = 0; i < 8; ++i) {
    acc[i][0] = bv0; acc[i][1] = bv1; acc[i][2] = bv2; acc[i][3] = bv3;
  }

  const float* Arow = &a_tile[rg * KP];     // thread's row i lives at rg + 4*i
  const float* Wp = W + cg * 4;

  // prologue: W chunk 0 in registers
  float4 w0 = *(const float4*)&Wp[0 * 256];
  float4 w1 = *(const float4*)&Wp[1 * 256];
  float4 w2 = *(const float4*)&Wp[2 * 256];
  float4 w3 = *(const float4*)&Wp[3 * 256];

  for (int k0 = 0; k0 < K; k0 += 4) {
    // branch-free prefetch of next chunk (last iter re-loads k=0, discarded)
    int kn = (k0 + 4 < K) ? (k0 + 4) : 0;
    float4 n0 = *(const float4*)&Wp[(kn + 0) * 256];
    float4 n1 = *(const float4*)&Wp[(kn + 1) * 256];
    float4 n2 = *(const float4*)&Wp[(kn + 2) * 256];
    float4 n3 = *(const float4*)&Wp[(kn + 3) * 256];
#pragma unroll
    for (int i = 0; i < 8; ++i) {
      float4 a = *(const float4*)&Arow[i * 4 * KP + k0];
      acc[i][0] += a.x * w0.x; acc[i][0] += a.y * w1.x;
      acc[i][0] += a.z * w2.x; acc[i][0] += a.w * w3.x;
      acc[i][1] += a.x * w0.y; acc[i][1] += a.y * w1.y;
      acc[i][1] += a.z * w2.y; acc[i][1] += a.w * w3.y;
      acc[i][2] += a.x * w0.z; acc[i][2] += a.y * w1.z;
      acc[i][2] += a.z * w2.z; acc[i][2] += a.w * w3.z;
      acc[i][3] += a.x * w0.w; acc[i][3] += a.y * w1.w;
      acc[i][3] += a.z * w2.w; acc[i][3] += a.w * w3.w;
    }
    w0 = n0; w1 = n1; w2 = n2; w3 = n3;
  }

#pragma unroll
  for (int i = 0; i < 8; ++i) {
    int row = r0 + rg + 4 * i;
    if (row < M) {
      float4 o = make_float4(acc[i][0], acc[i][1], acc[i][2], acc[i][3]);
      *(float4*)&out[(size_t)row * 256 + cg * 4] = o;
    }
  }
}

// ---------------- CSR build ----------------
__global__ void degree_kernel(const int* __restrict__ ei, int* __restrict__ deg) {
  int e = blockIdx.x * 256 + threadIdx.x;
  if (e < NE) atomicAdd(&deg[ei[NE + e]], 1);
}

__global__ __launch_bounds__(1024) void scan_kernel(
    const int* __restrict__ deg, int* __restrict__ rowstart) {
  __shared__ int buf0[1024];
  __shared__ int buf1[1024];
  int tid = threadIdx.x;
  const int per = (NN + 1023) / 1024;  // 49
  int s = tid * per, e = s + per; if (e > NN) e = NN; if (s > NN) s = NN;
  int sum = 0;
  for (int i = s; i < e; ++i) sum += deg[i];
  buf0[tid] = sum;
  __syncthreads();
  int* in = buf0; int* outb = buf1;
  for (int off = 1; off < 1024; off <<= 1) {
    int v = in[tid];
    if (tid >= off) v += in[tid - off];
    outb[tid] = v;
    __syncthreads();
    int* t = in; in = outb; outb = t;
  }
  int excl = in[tid] - sum;
  int run = excl;
  for (int i = s; i < e; ++i) { rowstart[i] = run; run += deg[i]; }
  if (tid == 1023) rowstart[NN] = in[1023];
}

__global__ void cursor_copy_kernel(const int* __restrict__ rowstart, int* __restrict__ cursor) {
  int i = blockIdx.x * 256 + threadIdx.x;
  if (i < NN) cursor[i] = rowstart[i];
}

// CSR fill: also materialize src and edge_attr in CSR order.
__global__ void fill_kernel(const int* __restrict__ ei, const float* __restrict__ ea,
                            int* __restrict__ cursor,
                            int* __restrict__ src_sorted, float* __restrict__ ea_sorted) {
  int e = blockIdx.x * 256 + threadIdx.x;
  if (e < NE) {
    int d = ei[NE + e];
    int pos = atomicAdd(&cursor[d], 1);
    src_sorted[pos] = ei[e];
    ea_sorted[pos] = ea[e];
  }
}

// ---------------- fused GATv2 edge phase: wave per dst node ----------------
__global__ __launch_bounds__(256) void gat_fused_kernel(
    const int* __restrict__ rowstart, const int* __restrict__ src_sorted,
    const float* __restrict__ ea_sorted,
    const float* __restrict__ xl, const float* __restrict__ xr,
    const float* __restrict__ we, const float* __restrict__ att,
    const float* __restrict__ bias, float* __restrict__ out) {
  int node = (blockIdx.x * 256 + threadIdx.x) >> 6;
  int lane = threadIdx.x & 63;
  int r0 = rowstart[node], r1 = rowstart[node + 1];
  const float4* xl4 = (const float4*)xl;
  float4 r = ((const float4*)xr)[node * 64 + lane];
  float4 wv = ((const float4*)we)[lane];
  float4 at = ((const float4*)att)[lane];
  float4 acc = make_float4(0.f, 0.f, 0.f, 0.f);
  float denom = 0.f;

  auto edge_step = [&](float eav, float4 a) {
    float s0 = a.x + r.x + eav * wv.x;
    float s1 = a.y + r.y + eav * wv.y;
    float s2 = a.z + r.z + eav * wv.z;
    float s3 = a.w + r.w + eav * wv.w;
    s0 = s0 > 0.f ? s0 : 0.2f * s0;
    s1 = s1 > 0.f ? s1 : 0.2f * s1;
    s2 = s2 > 0.f ? s2 : 0.2f * s2;
    s3 = s3 > 0.f ? s3 : 0.2f * s3;
    float p = s0 * at.x + s1 * at.y + s2 * at.z + s3 * at.w;
#pragma unroll
    for (int off = 8; off; off >>= 1) p += __shfl_xor(p, off, 16);
    float ex = __expf(p);
    denom += ex;
    acc.x += ex * a.x; acc.y += ex * a.y; acc.z += ex * a.z; acc.w += ex * a.w;
  };

  int i = r0;
  for (; i + 2 <= r1; i += 2) {           // pairwise: 2 gathers in flight
    int s0i = src_sorted[i];
    int s1i = src_sorted[i + 1];
    float e0 = ea_sorted[i];
    float e1 = ea_sorted[i + 1];
    float4 a0 = xl4[(size_t)s0i * 64 + lane];
    float4 a1 = xl4[(size_t)s1i * 64 + lane];
    edge_step(e0, a0);
    edge_step(e1, a1);
  }
  if (i < r1) {
    int s0i = src_sorted[i];
    float e0 = ea_sorted[i];
    float4 a0 = xl4[(size_t)s0i * 64 + lane];
    edge_step(e0, a0);
  }

  float inv = 1.f / (denom + 1e-16f);
  float4 bv = ((const float4*)bias)[lane];
  float4 o;
  o.x = fmaxf(acc.x * inv + bv.x, 0.f);
  o.y = fmaxf(acc.y * inv + bv.y, 0.f);
  o.z = fmaxf(acc.z * inv + bv.z, 0.f);
  o.w = fmaxf(acc.w * inv + bv.w, 0.f);
  ((float4*)out)[(size_t)node * 64 + lane] = o;
}

// ---------------- segment bounds via binary search (batch is sorted) ----------------
__global__ void seg_bounds_kernel(const int* __restrict__ batch, int* __restrict__ bounds) {
  int g = threadIdx.x;                 // 0..GG inclusive
  if (g > GG) return;
  int lo = 0, hi = NN;
  while (lo < hi) {                    // first index with batch[i] >= g
    int mid = (lo + hi) >> 1;
    if (batch[mid] < g) lo = mid + 1; else hi = mid;
  }
  bounds[g] = lo;
}

__global__ __launch_bounds__(256) void pool_kernel(
    const float* __restrict__ h, const int* __restrict__ batch,
    float* __restrict__ pool) {
  int start = blockIdx.x * 256;
  int end = start + 256; if (end > NN) end = NN;
  int tid = threadIdx.x;
  int cur = batch[start];
  float acc = 0.f;
  for (int n = start; n < end; ++n) {
    int b = batch[n];
    if (b != cur) {
      atomicAdd(&pool[cur * 256 + tid], acc);
      acc = 0.f; cur = b;
    }
    acc += h[n * 256 + tid];
  }
  atomicAdd(&pool[cur * 256 + tid], acc);
}

// ---------------- final MLP: one block (128 thr) per graph ----------------
__global__ __launch_bounds__(128) void mlp_kernel(
    const float* __restrict__ pool, const int* __restrict__ bounds,
    const float* __restrict__ p1w, const float* __restrict__ p1b,
    const float* __restrict__ lng, const float* __restrict__ lnb,
    const float* __restrict__ p2w, const float* __restrict__ p2b,
    const float* __restrict__ hw, const float* __restrict__ hb,
    float* __restrict__ out) {
  __shared__ float sg[256];
  __shared__ float red[128];
  __shared__ float sz[128];
  __shared__ float s2[64];
  int b = blockIdx.x, tid = threadIdx.x;
  float cntf = (float)(bounds[b + 1] - bounds[b]);
  float invc = 1.f / fmaxf(cntf, 1.f);
  for (int i = tid; i < 256; i += 128) sg[i] = pool[b * 256 + i] * invc;
  __syncthreads();
  float z = p1b[tid];
  for (int k = 0; k < 256; ++k) z += sg[k] * p1w[k * 128 + tid];
  red[tid] = z; __syncthreads();
  for (int off = 64; off; off >>= 1) { if (tid < off) red[tid] += red[tid + off]; __syncthreads(); }
  float mu = red[0] * (1.f / 128.f);
  __syncthreads();
  float d = z - mu;
  red[tid] = d * d; __syncthreads();
  for (int off = 64; off; off >>= 1) { if (tid < off) red[tid] += red[tid + off]; __syncthreads(); }
  float var = red[0] * (1.f / 128.f);
  float zn = d * rsqrtf(var + 1e-5f) * lng[tid] + lnb[tid];
  sz[tid] = fmaxf(zn, 0.f);
  __syncthreads();
  if (tid < 64) {
    float a = p2b[tid];
    for (int k = 0; k < 128; ++k) a += sz[k] * p2w[k * 64 + tid];
    s2[tid] = fmaxf(a, 0.f);
  }
  __syncthreads();
  if (tid < 64) {
    float p = s2[tid] * hw[tid];
    for (int off = 32; off; off >>= 1) p += __shfl_down(p, off, 64);
    if (tid == 0) out[b] = p + hb[0];
  }
}

extern "C" void kernel_launch(void* const* d_in, const int* in_sizes, int n_in,
                              void* d_out, int out_size, void* d_ws, size_t ws_size,
                              hipStream_t stream) {
  const float* x      = (const float*)d_in[0];
  const int*   ei     = (const int*)d_in[1];
  const float* ea     = (const float*)d_in[2];
  const int*   batch  = (const int*)d_in[3];
  const float* enc_w  = (const float*)d_in[4];
  const float* enc_b  = (const float*)d_in[5];
  const float* g1_wl  = (const float*)d_in[6];
  const float* g1_bl  = (const float*)d_in[7];
  const float* g1_wr  = (const float*)d_in[8];
  const float* g1_we  = (const float*)d_in[9];
  const float* g1_att = (const float*)d_in[10];
  const float* g1_b   = (const float*)d_in[11];
  const float* g2_wl  = (const float*)d_in[12];
  const float* g2_bl  = (const float*)d_in[13];
  const float* g2_wr  = (const float*)d_in[14];
  const float* g2_we  = (const float*)d_in[15];
  const float* g2_att = (const float*)d_in[16];
  const float* g2_b   = (const float*)d_in[17];
  const float* p1_w   = (const float*)d_in[18];
  const float* p1_b   = (const float*)d_in[19];
  const float* ln_g   = (const float*)d_in[20];
  const float* ln_b   = (const float*)d_in[21];
  const float* p2_w   = (const float*)d_in[22];
  const float* p2_b   = (const float*)d_in[23];
  const float* head_w = (const float*)d_in[24];
  const float* head_b = (const float*)d_in[25];
  float* out = (float*)d_out;

  char* ws = (char*)d_ws;
  size_t off = 0;
  auto alloc = [&](size_t bytes) -> void* {
    void* p = ws + off;
    off = (off + bytes + 255) & ~(size_t)255;
    return p;
  };
  float* h0        = (float*)alloc((size_t)NN * 64 * 4);
  float* hbuf      = (float*)alloc((size_t)NN * HC * 4);
  float* xl        = (float*)alloc((size_t)NN * HC * 4);
  float* xr        = (float*)alloc((size_t)NN * HC * 4);
  float* pool      = (float*)alloc((size_t)GG * HC * 4);
  int*   deg       = (int*)alloc((size_t)NN * 4);
  int*   rowstart  = (int*)alloc((size_t)(NN + 1) * 4);
  int*   cursor    = (int*)alloc((size_t)NN * 4);
  int*   src_sorted= (int*)alloc((size_t)NE * 4);
  float* ea_sorted = (float*)alloc((size_t)NE * 4);
  int*   bounds    = (int*)alloc((size_t)(GG + 1) * 4);

  hipMemsetAsync(deg, 0, (size_t)NN * 4, stream);
  hipMemsetAsync(pool, 0, (size_t)GG * HC * 4, stream);

  // encoder
  encoder_kernel<<<NN * 64 / 256, 256, 0, stream>>>(x, enc_w, enc_b, h0);

  // CSR build (shared by both layers)
  degree_kernel<<<(NE + 255) / 256, 256, 0, stream>>>(ei, deg);
  scan_kernel<<<1, 1024, 0, stream>>>(deg, rowstart);
  cursor_copy_kernel<<<(NN + 255) / 256, 256, 0, stream>>>(rowstart, cursor);
  fill_kernel<<<(NE + 255) / 256, 256, 0, stream>>>(ei, ea, cursor, src_sorted, ea_sorted);

  // graph segment bounds (batch is sorted)
  seg_bounds_kernel<<<1, GG + 1, 0, stream>>>(batch, bounds);

  const int MMB = (NN + 31) / 32;  // matmul blocks

  // ---- GAT layer 1 (K=64) ----
  matmul_rb_kernel<64><<<MMB, 256, 0, stream>>>(h0, g1_wl, g1_bl, xl, NN);
  matmul_rb_kernel<64><<<MMB, 256, 0, stream>>>(h0, g1_wr, nullptr, xr, NN);
  gat_fused_kernel<<<NN / 4, 256, 0, stream>>>(rowstart, src_sorted, ea_sorted,
                                               xl, xr, g1_we, g1_att, g1_b, hbuf);

  // ---- GAT layer 2 (K=256) ----
  matmul_rb_kernel<256><<<MMB, 256, 0, stream>>>(hbuf, g2_wl, g2_bl, xl, NN);
  matmul_rb_kernel<256><<<MMB, 256, 0, stream>>>(hbuf, g2_wr, nullptr, xr, NN);
  gat_fused_kernel<<<NN / 4, 256, 0, stream>>>(rowstart, src_sorted, ea_sorted,
                                               xl, xr, g2_we, g2_att, g2_b, hbuf);

  // ---- pooling + MLP head ----
  pool_kernel<<<(NN + 255) / 256, 256, 0, stream>>>(hbuf, batch, pool);
  mlp_kernel<<<GG, 128, 0, stream>>>(pool, bounds, p1_w, p1_b, ln_g, ln_b,
                                     p2_w, p2_b, head_w, head_b, out);
}